// Round 1
// baseline (230.683 us; speedup 1.0000x reference)
//
#include <hip/hip_runtime.h>
#include <hip/hip_bf16.h>

#define LN 96
#define BN 32
#define DM 128
#define EPN 95   // edges per receiver node = L-1

typedef __attribute__((ext_vector_type(8))) short s16x8;
typedef __attribute__((ext_vector_type(4))) float f32x4;

__device__ __forceinline__ float eluf(float x) {
    return x > 0.f ? x : __expf(x) - 1.f;
}

__device__ __forceinline__ unsigned short f2bf(float f) {
    unsigned int u = __float_as_uint(f);
    unsigned int r = (u + 0x7fff + ((u >> 16) & 1)) >> 16;
    return (unsigned short)r;
}

// ---------------- weight convert: w2bt[m][n][k] = bf16(eW2[m][k][n]) ----------------
__global__ void conv_w2_kernel(const float* __restrict__ eW2, unsigned short* __restrict__ w2bt) {
    int idx = blockIdx.x * 256 + threadIdx.x;   // < 3*128*128 = 49152
    int m = idx >> 14;
    int rem = idx & 16383;
    int n = rem >> 7, k = rem & 127;
    w2bt[idx] = f2bf(eW2[(m << 14) + (k << 7) + n]);
}

// ---------------- node-level stage ----------------
// mode 0: in = inputs (L,B,4); layer1 K=4 (W0a), layer2 (W0b); proj = eW1[0]
// mode 1: in = g (B,L,128);   layer1 (nW1[i]), layer2 (nW2[i]); proj = eW1[i+1] or fW1
// writes hs = h@Wp_top, hr = h@Wp_bot + bp
__global__ void node_stage_kernel(const float* __restrict__ in,
                                  const float* __restrict__ W1, const float* __restrict__ b1,
                                  const float* __restrict__ W2, const float* __restrict__ b2,
                                  const float* __restrict__ Wp, const float* __restrict__ bp,
                                  float* __restrict__ hs, float* __restrict__ hr,
                                  int mode) {
    __shared__ float act[16][DM];
    const int t = threadIdx.x;
    const int col = t & 127;
    const int rh = t >> 7;              // 0/1: which 8-row half
    const int row0 = blockIdx.x * 16;   // global row (b*96+l)

    if (mode == 0) {
        if (t < 64) {
            int rr = t >> 2, k = t & 3;
            int row = row0 + rr;
            int b = row / LN, l = row - b * LN;
            act[rr][k] = in[(l * BN + b) * 4 + k];
        }
    } else {
        for (int i = 0; i < 8; ++i) {
            int rr = rh * 8 + i;
            act[rr][col] = in[(size_t)(row0 + rr) * DM + col];
        }
    }
    __syncthreads();

    float acc[8];
    // layer 1
    {
        const int K = (mode == 0) ? 4 : DM;
        float bb = b1[col];
        for (int i = 0; i < 8; ++i) acc[i] = bb;
        for (int k = 0; k < K; ++k) {
            float w = W1[k * DM + col];
            for (int i = 0; i < 8; ++i) acc[i] += act[rh * 8 + i][k] * w;
        }
        for (int i = 0; i < 8; ++i) acc[i] = eluf(acc[i]);
    }
    __syncthreads();
    for (int i = 0; i < 8; ++i) act[rh * 8 + i][col] = acc[i];
    __syncthreads();
    // layer 2
    {
        float bb = b2[col];
        for (int i = 0; i < 8; ++i) acc[i] = bb;
        for (int k = 0; k < DM; ++k) {
            float w = W2[k * DM + col];
            for (int i = 0; i < 8; ++i) acc[i] += act[rh * 8 + i][k] * w;
        }
        for (int i = 0; i < 8; ++i) acc[i] = eluf(acc[i]);
    }
    __syncthreads();
    for (int i = 0; i < 8; ++i) act[rh * 8 + i][col] = acc[i];
    __syncthreads();
    // projections (send / recv halves of Wp)
    float aS[8], aR[8];
    {
        float bb = bp[col];
        for (int i = 0; i < 8; ++i) { aS[i] = 0.f; aR[i] = bb; }
        for (int k = 0; k < DM; ++k) {
            float ws = Wp[k * DM + col];
            float wr = Wp[(DM + k) * DM + col];
            for (int i = 0; i < 8; ++i) {
                float a = act[rh * 8 + i][k];
                aS[i] += a * ws;
                aR[i] += a * wr;
            }
        }
    }
    for (int i = 0; i < 8; ++i) {
        size_t o = (size_t)(row0 + rh * 8 + i) * DM + col;
        hs[o] = aS[i];
        hr[o] = aR[i];
    }
}

// ---------------- edge kernel: per (b,r): y1=elu(hs[send]+hr[r]); y2=elu(y1@eW2+b2); g[b][r]=mean_rows(y2) ----------------
__global__ __launch_bounds__(256) void edge_kernel(
    const float* __restrict__ hs, const float* __restrict__ hr,
    const unsigned short* __restrict__ w2bt,   // [128][128] bf16, n-major (transposed)
    const float* __restrict__ b2,
    float* __restrict__ g) {
    __shared__ char y1lds[96 * 256];   // 96 rows x 128 bf16, XOR-swizzled
    __shared__ float hrbuf[DM];
    const int r = blockIdx.x, b = blockIdx.y;
    const int t = threadIdx.x;
    const int l = t & 63, w = t >> 6;
    const int n0 = w * 32;
    const int l15 = l & 15, kgrp = l >> 4;

    // B-fragments (held in registers for the whole kernel), from L2-hot weights
    s16x8 bf[2][4];
#pragma unroll
    for (int nt = 0; nt < 2; ++nt)
#pragma unroll
        for (int ks = 0; ks < 4; ++ks)
            bf[nt][ks] = *(const s16x8*)(w2bt + (size_t)(n0 + nt * 16 + l15) * DM + ks * 32 + kgrp * 8);

    if (t < DM) hrbuf[t] = hr[((size_t)b * LN + r) * DM + t];
    __syncthreads();

    // build y1 tile (rows = edges with recv=r; row 95 = zero pad)
    {
        int row = t >> 1;
        int half = (t & 1) * 64;
        if (row < EPN) {
            int j = row + (row >= r);
            const float* src = hs + ((size_t)b * LN + j) * DM + half;
#pragma unroll
            for (int c8 = 0; c8 < 8; ++c8) {
                int c0 = half + c8 * 8;
                float4 f0 = *(const float4*)(src + c8 * 8);
                float4 f1 = *(const float4*)(src + c8 * 8 + 4);
                union { unsigned short us[8]; uint4 v; } pk;
                pk.us[0] = f2bf(eluf(f0.x + hrbuf[c0 + 0]));
                pk.us[1] = f2bf(eluf(f0.y + hrbuf[c0 + 1]));
                pk.us[2] = f2bf(eluf(f0.z + hrbuf[c0 + 2]));
                pk.us[3] = f2bf(eluf(f0.w + hrbuf[c0 + 3]));
                pk.us[4] = f2bf(eluf(f1.x + hrbuf[c0 + 4]));
                pk.us[5] = f2bf(eluf(f1.y + hrbuf[c0 + 5]));
                pk.us[6] = f2bf(eluf(f1.z + hrbuf[c0 + 6]));
                pk.us[7] = f2bf(eluf(f1.w + hrbuf[c0 + 7]));
                *(uint4*)(y1lds + row * 256 + ((c0 * 2) ^ ((row & 7) << 4))) = pk.v;
            }
        } else if (row == EPN) {
#pragma unroll
            for (int c8 = 0; c8 < 8; ++c8) {
                int c0 = half + c8 * 8;
                *(uint4*)(y1lds + row * 256 + ((c0 * 2) ^ ((row & 7) << 4))) = make_uint4(0, 0, 0, 0);
            }
        }
    }
    __syncthreads();

    f32x4 acc[6][2] = {};
#pragma unroll
    for (int mt = 0; mt < 6; ++mt) {
        int arow = mt * 16 + l15;
        const char* rb = y1lds + arow * 256;
        int swz = (arow & 7) << 4;
#pragma unroll
        for (int ks = 0; ks < 4; ++ks) {
            s16x8 a = *(const s16x8*)(rb + (((ks * 32 + kgrp * 8) * 2) ^ swz));
            acc[mt][0] = __builtin_amdgcn_mfma_f32_16x16x32_bf16(a, bf[0][ks], acc[mt][0], 0, 0, 0);
            acc[mt][1] = __builtin_amdgcn_mfma_f32_16x16x32_bf16(a, bf[1][ks], acc[mt][1], 0, 0, 0);
        }
    }

    // epilogue: +b2, elu, column-mean over 95 rows
    float b2c0 = b2[n0 + l15], b2c1 = b2[n0 + 16 + l15];
    float cs0 = 0.f, cs1 = 0.f;
#pragma unroll
    for (int mt = 0; mt < 6; ++mt) {
#pragma unroll
        for (int i = 0; i < 4; ++i) {
            int rowi = mt * 16 + kgrp * 4 + i;   // C/D layout: col=lane&15, row=(lane>>4)*4+i
            if (rowi < EPN) {
                cs0 += eluf(acc[mt][0][i] + b2c0);
                cs1 += eluf(acc[mt][1][i] + b2c1);
            }
        }
    }
    cs0 += __shfl_xor(cs0, 16); cs0 += __shfl_xor(cs0, 32);
    cs1 += __shfl_xor(cs1, 16); cs1 += __shfl_xor(cs1, 32);
    if (l < 16) {
        float* go = g + ((size_t)b * LN + r) * DM + n0;
        go[l] = cs0 * (1.f / 95.f);
        go[16 + l] = cs1 * (1.f / 95.f);
    }
}

// ---------------- final: out[b][e][c] = elu(hs_f[send]+hr_f[recv]) @ fW2 + fb2 ----------------
__global__ void final_kernel(const float* __restrict__ hs, const float* __restrict__ hr,
                             const float* __restrict__ fW2, const float* __restrict__ fb2,
                             float* __restrict__ out) {
    __shared__ float w2l[DM * 6];
    __shared__ float hrbuf[DM];
    const int r = blockIdx.x, b = blockIdx.y;
    const int t = threadIdx.x;   // 128 threads
    hrbuf[t] = hr[((size_t)b * LN + r) * DM + t];
    for (int c = 0; c < 6; ++c) w2l[t * 6 + c] = fW2[t * 6 + c];
    __syncthreads();
    int k = t;
    if (k < EPN) {
        int j = k + (k >= r);
        const float* src = hs + ((size_t)b * LN + j) * DM;
        float acc[6];
        for (int c = 0; c < 6; ++c) acc[c] = fb2[c];
        for (int d0 = 0; d0 < DM; d0 += 4) {
            float4 f = *(const float4*)(src + d0);
            float v0 = eluf(f.x + hrbuf[d0 + 0]);
            float v1 = eluf(f.y + hrbuf[d0 + 1]);
            float v2 = eluf(f.z + hrbuf[d0 + 2]);
            float v3 = eluf(f.w + hrbuf[d0 + 3]);
            for (int c = 0; c < 6; ++c)
                acc[c] += v0 * w2l[(d0 + 0) * 6 + c] + v1 * w2l[(d0 + 1) * 6 + c]
                        + v2 * w2l[(d0 + 2) * 6 + c] + v3 * w2l[(d0 + 3) * 6 + c];
        }
        float* o = out + (((size_t)b * (LN * EPN)) + r * EPN + k) * 6;
        for (int c = 0; c < 6; ++c) o[c] = acc[c];
    }
}

extern "C" void kernel_launch(void* const* d_in, const int* in_sizes, int n_in,
                              void* d_out, int out_size, void* d_ws, size_t ws_size,
                              hipStream_t stream) {
    const float* inputs = (const float*)d_in[0];
    // d_in[1] = rel_rec, d_in[2] = rel_send : structure known, unused
    const float* W0a = (const float*)d_in[3];
    const float* b0a = (const float*)d_in[4];
    const float* W0b = (const float*)d_in[5];
    const float* b0b = (const float*)d_in[6];
    const float* eW1 = (const float*)d_in[7];
    const float* eb1 = (const float*)d_in[8];
    const float* eW2 = (const float*)d_in[9];
    const float* eb2 = (const float*)d_in[10];
    const float* nW1 = (const float*)d_in[11];
    const float* nb1 = (const float*)d_in[12];
    const float* nW2 = (const float*)d_in[13];
    const float* nb2 = (const float*)d_in[14];
    const float* fW1 = (const float*)d_in[15];
    const float* fb1 = (const float*)d_in[16];
    const float* fW2 = (const float*)d_in[17];
    const float* fb2 = (const float*)d_in[18];
    float* out = (float*)d_out;

    const int NR = BN * LN;            // 3072 node rows
    float* hs = (float*)d_ws;          // (B,L,128) f32
    float* hr = hs + NR * DM;          // (B,L,128) f32
    float* g  = hr + NR * DM;          // (B,L,128) f32
    unsigned short* w2bt = (unsigned short*)(g + NR * DM);   // 3 x [128][128] bf16 transposed

    dim3 eg(LN, BN);

    conv_w2_kernel<<<192, 256, 0, stream>>>(eW2, w2bt);
    // block 0
    node_stage_kernel<<<192, 256, 0, stream>>>(inputs, W0a, b0a, W0b, b0b, eW1, eb1, hs, hr, 0);
    edge_kernel<<<eg, 256, 0, stream>>>(hs, hr, w2bt, eb2, g);
    // block 1
    node_stage_kernel<<<192, 256, 0, stream>>>(g, nW1, nb1, nW2, nb2, eW1 + 32768, eb1 + 128, hs, hr, 1);
    edge_kernel<<<eg, 256, 0, stream>>>(hs, hr, w2bt + 16384, eb2 + 128, g);
    // block 2
    node_stage_kernel<<<192, 256, 0, stream>>>(g, nW1 + 16384, nb1 + 128, nW2 + 16384, nb2 + 128, eW1 + 65536, eb1 + 256, hs, hr, 1);
    edge_kernel<<<eg, 256, 0, stream>>>(hs, hr, w2bt + 32768, eb2 + 256, g);
    // final
    node_stage_kernel<<<192, 256, 0, stream>>>(g, nW1 + 32768, nb1 + 256, nW2 + 32768, nb2 + 256, fW1, fb1, hs, hr, 1);
    final_kernel<<<eg, 128, 0, stream>>>(hs, hr, fW2, fb2, out);
}